// Round 3
// baseline (364.517 us; speedup 1.0000x reference)
//
#include <hip/hip_runtime.h>
#include <hip/hip_bf16.h>

typedef __attribute__((ext_vector_type(8))) short short8v;
typedef __attribute__((ext_vector_type(4))) float float4v;

struct SedTab { signed char sgn[256]; signed char idx[256]; };

__device__ inline unsigned short f2bf(float f) {
    __hip_bfloat16 h = __float2bfloat16(f);
    return *reinterpret_cast<unsigned short*>(&h);
}
__device__ inline float bf2f(unsigned short u) {
    union { unsigned int i; float f; } x; x.i = ((unsigned)u) << 16; return x.f;
}

#define GLOAD_LDS16(g, l) __builtin_amdgcn_global_load_lds( \
    (const __attribute__((address_space(1))) void*)(g), \
    (__attribute__((address_space(3))) void*)(l), 16, 0, 0)

#define VMCNT(n) asm volatile("s_waitcnt vmcnt(" #n ")" ::: "memory")

// ---------------- Kernel P: build BigT (n-major) bf16 ----------------
__global__ __launch_bounds__(256) void build_bigT(
    const float* __restrict__ w_comp, unsigned short* __restrict__ bigT, SedTab tab)
{
    int e = blockIdx.x * 256 + threadIdx.x;
    if (e >= 1536 * 1536) return;
    int n = e / 1536, k = e - n * 1536;
    int t_out = n / 96, c = n - t_out * 96;
    int t_in = k / 96, m = k - t_in * 96;
    int i = tab.idx[t_in * 16 + t_out];
    float s = (float)tab.sgn[t_in * 16 + t_out];
    float v = s * w_comp[(i * 96 + m) * 96 + c];
    bigT[e] = f2bf(v);
}

// ---------------- Kernel W: window + cast to bf16 ----------------
__global__ __launch_bounds__(256) void window_cast(
    const float* __restrict__ x, unsigned short* __restrict__ xw)
{
    __shared__ unsigned short lds[96][260];
    int blk = blockIdx.x;
    int s1 = blk & 3, hh = (blk >> 2) & 63, b = blk >> 8;
    const float* src = x + (size_t)b * 6291456 + (size_t)(4 * hh + s1) * 256;

    for (int i = threadIdx.x; i < 6144; i += 256) {
        int m = i >> 6;
        int q = (i & 63) << 2;
        float4 v = *(const float4*)(src + (size_t)m * 65536 + q);
        lds[m][q + 0] = f2bf(v.x);
        lds[m][q + 1] = f2bf(v.y);
        lds[m][q + 2] = f2bf(v.z);
        lds[m][q + 3] = f2bf(v.w);
    }
    __syncthreads();
    size_t rowbase = (size_t)((b * 64 + hh) * 64) * 1536 + (size_t)s1 * 384;
    for (int i = threadIdx.x; i < 3072; i += 256) {
        int ww = i / 48, g = i - ww * 48;
        int s2 = g / 12, mg = (g - s2 * 12) * 8;
        int qq = 4 * ww + s2;
        short8v pk;
        #pragma unroll
        for (int j = 0; j < 8; ++j) pk[j] = (short)lds[mg + j][qq];
        *(short8v*)(xw + rowbase + (size_t)ww * 1536 + s2 * 96 + mg) = pk;
    }
}

// ---------------- Kernel G: phased-pipeline bf16 GEMM + GELU ----------------
// M=32768, N=1536, K=1536. BM=128, BN=256, BK=64, 512 thr (8 waves, 2Mx4N).
// 3 LDS buffers: tile t reads slot t%3, staging writes (t+2)%3 (never same).
// Counted vmcnt(6) in steady state (tile t+2's 6 loads in flight), never 0
// until drain. XOR swizzle: linear gload_lds dest + pre-swizzled global src
// kc = ((c&7)^(row&7))<<3; reads XOR the same involution (rule #21).
__global__ __launch_bounds__(512, 2) void gemm_sed8(
    const unsigned short* __restrict__ A,
    const unsigned short* __restrict__ Bt,
    unsigned short* __restrict__ Yg)
{
    __shared__ unsigned short As[3][128 * 64];   //  48 KiB
    __shared__ unsigned short Bs[3][256 * 64];   //  96 KiB
    const int t = threadIdx.x;
    const int lane = t & 63, w = t >> 6;
    const int wm = w >> 2, wn = w & 3;           // 2 x 4 waves
    const int lr = lane & 15, lg = lane >> 4;

    // XCD-aware bijective swizzle (1536 % 8 == 0), nt-major chunks:
    // each XCD works mostly within one B-panel (786 KB, L2-resident).
    const int bid = blockIdx.x;
    const int wg = (bid & 7) * 192 + (bid >> 3);
    const int nt = wg >> 8, mt = wg & 255;       // N/256=6 nt, M/128=256 mt
    const int m0 = mt * 128, n0 = nt * 256;

    float4v acc[4][4];
    #pragma unroll
    for (int i = 0; i < 4; ++i)
        #pragma unroll
        for (int j = 0; j < 4; ++j) acc[i][j] = (float4v)0.0f;

    auto stageA = [&](int kt, int slot, int i) {  // A-tile 128x64 = 1024 chunks, i in [0,2)
        const int c = t + i * 512;
        const int row = c >> 3;
        const int kc = (((c & 7) ^ (row & 7)) << 3);
        GLOAD_LDS16(A + (size_t)(m0 + row) * 1536 + kt * 64 + kc,
                    (char*)&As[slot][0] + c * 16);
    };
    auto stageB = [&](int kt, int slot, int i) {  // B-tile 256x64 = 2048 chunks, i in [0,4)
        const int c = t + i * 512;
        const int row = c >> 3;
        const int kc = (((c & 7) ^ (row & 7)) << 3);
        GLOAD_LDS16(Bt + (size_t)(n0 + row) * 1536 + kt * 64 + kc,
                    (char*)&Bs[slot][0] + c * 16);
    };

    // prologue: stage tiles 0 and 1 (6 loads each); tile 0 complete, tile 1 in flight
    stageA(0, 0, 0); stageA(0, 0, 1);
    stageB(0, 0, 0); stageB(0, 0, 1); stageB(0, 0, 2); stageB(0, 0, 3);
    stageA(1, 1, 0); stageA(1, 1, 1);
    stageB(1, 1, 0); stageB(1, 1, 1); stageB(1, 1, 2); stageB(1, 1, 3);
    VMCNT(6);
    __builtin_amdgcn_s_barrier();

    int slot = 0;
    for (int kt = 0; kt < 24; ++kt) {
        const int ps = (slot == 0) ? 2 : slot - 1;   // (kt+2) % 3
        const int pf = kt + 2;
        const bool st = (pf < 24);

        // ---- phase A: n-frags 0,1 (12 ds_read_b128 + 3 stage loads) ----
        short8v a[4][2], b0[2][2];
        #pragma unroll
        for (int mf = 0; mf < 4; ++mf)
            #pragma unroll
            for (int ks = 0; ks < 2; ++ks) {
                const int row = wm * 64 + mf * 16 + lr;
                const int col = (ks * 32 + lg * 8) ^ ((row & 7) << 3);
                a[mf][ks] = *(const short8v*)(&As[slot][row * 64 + col]);
            }
        #pragma unroll
        for (int nf = 0; nf < 2; ++nf)
            #pragma unroll
            for (int ks = 0; ks < 2; ++ks) {
                const int row = wn * 64 + nf * 16 + lr;
                const int col = (ks * 32 + lg * 8) ^ ((row & 7) << 3);
                b0[nf][ks] = *(const short8v*)(&Bs[slot][row * 64 + col]);
            }
        if (st) { stageA(pf, ps, 0); stageA(pf, ps, 1); stageB(pf, ps, 0); }
        __builtin_amdgcn_s_barrier();
        __builtin_amdgcn_s_setprio(1);
        #pragma unroll
        for (int ks = 0; ks < 2; ++ks)
            #pragma unroll
            for (int mf = 0; mf < 4; ++mf)
                #pragma unroll
                for (int nf = 0; nf < 2; ++nf)
                    acc[mf][nf] = __builtin_amdgcn_mfma_f32_16x16x32_bf16(
                        a[mf][ks], b0[nf][ks], acc[mf][nf], 0, 0, 0);
        __builtin_amdgcn_s_setprio(0);
        __builtin_amdgcn_s_barrier();

        // ---- phase B: n-frags 2,3 (4 ds_read_b128 + 3 stage loads) ----
        short8v b1[2][2];
        #pragma unroll
        for (int nf = 0; nf < 2; ++nf)
            #pragma unroll
            for (int ks = 0; ks < 2; ++ks) {
                const int row = wn * 64 + (nf + 2) * 16 + lr;
                const int col = (ks * 32 + lg * 8) ^ ((row & 7) << 3);
                b1[nf][ks] = *(const short8v*)(&Bs[slot][row * 64 + col]);
            }
        if (st) { stageB(pf, ps, 1); stageB(pf, ps, 2); stageB(pf, ps, 3); }
        // tile kt+1 readiness: own tile-(kt+1) loads retired, tile-(kt+2)'s 6 in flight
        if (kt < 22)       { VMCNT(6); }
        else if (kt == 22) { VMCNT(0); }
        __builtin_amdgcn_s_barrier();
        __builtin_amdgcn_s_setprio(1);
        #pragma unroll
        for (int ks = 0; ks < 2; ++ks)
            #pragma unroll
            for (int mf = 0; mf < 4; ++mf)
                #pragma unroll
                for (int nf = 0; nf < 2; ++nf)
                    acc[mf][nf + 2] = __builtin_amdgcn_mfma_f32_16x16x32_bf16(
                        a[mf][ks], b1[nf][ks], acc[mf][nf + 2], 0, 0, 0);
        __builtin_amdgcn_s_setprio(0);
        __builtin_amdgcn_s_barrier();

        slot = (slot == 2) ? 0 : slot + 1;
    }

    // epilogue: exact GELU, cast bf16, store
    #pragma unroll
    for (int mf = 0; mf < 4; ++mf) {
        #pragma unroll
        for (int r = 0; r < 4; ++r) {
            const int gm = m0 + wm * 64 + mf * 16 + lg * 4 + r;
            #pragma unroll
            for (int nf = 0; nf < 4; ++nf) {
                const int gn = n0 + wn * 64 + nf * 16 + lr;
                float v = acc[mf][nf][r];
                float g = 0.5f * v * (1.0f + erff(v * 0.70710678118654752f));
                Yg[(size_t)gm * 1536 + gn] = f2bf(g);
            }
        }
    }
}

// ---------------- Kernel R: MFMA projection + bias + NCHW store ----------------
__global__ __launch_bounds__(256, 2) void proj_mfma(
    const unsigned short* __restrict__ Yg,
    const float* __restrict__ pw, const float* __restrict__ pb,
    float* __restrict__ out)
{
    __shared__ unsigned short gys[256 * 104];
    __shared__ unsigned short pws[96 * 104];
    __shared__ float pbs[96];

    const int blk = blockIdx.x;
    const int s1 = blk & 3, hh = (blk >> 2) & 63, b = blk >> 8;
    const int t = threadIdx.x;
    const int lane = t & 63, w = t >> 6;
    const int lr = lane & 15;

    for (int i = t; i < 9216; i += 256) {
        int r = i / 96, c = i - r * 96;
        pws[r * 104 + c] = f2bf(pw[i]);
    }
    if (t < 96) pbs[t] = pb[t];

    size_t rowbase = (size_t)((b * 64 + hh) * 64) * 1536 + (size_t)s1 * 384;
    for (int i = t; i < 3072; i += 256) {
        int ww = i / 48, v = i - ww * 48;
        short8v pk = *(const short8v*)(Yg + rowbase + (size_t)ww * 1536 + v * 8);
        int s2 = v / 12;
        int c = (v - s2 * 12) * 8;
        int q = 4 * ww + s2;
        *(short8v*)(&gys[q * 104 + c]) = pk;
    }
    __syncthreads();

    float4v acc[6][4];
    #pragma unroll
    for (int i = 0; i < 6; ++i)
        #pragma unroll
        for (int j = 0; j < 4; ++j) acc[i][j] = (float4v)0.0f;

    #pragma unroll
    for (int ks = 0; ks < 3; ++ks) {
        const int lk = ks * 32 + ((lane >> 4) << 3);
        short8v af[6], bf[4];
        #pragma unroll
        for (int mf = 0; mf < 6; ++mf)
            af[mf] = *(const short8v*)(&pws[(mf * 16 + lr) * 104 + lk]);
        #pragma unroll
        for (int nf = 0; nf < 4; ++nf)
            bf[nf] = *(const short8v*)(&gys[(w * 64 + nf * 16 + lr) * 104 + lk]);
        #pragma unroll
        for (int mf = 0; mf < 6; ++mf)
            #pragma unroll
            for (int nf = 0; nf < 4; ++nf)
                acc[mf][nf] = __builtin_amdgcn_mfma_f32_16x16x32_bf16(
                    af[mf], bf[nf], acc[mf][nf], 0, 0, 0);
    }

    const int p = 4 * hh + s1;
    const size_t obase = (size_t)b * 6291456 + (size_t)p * 256;
    #pragma unroll
    for (int mf = 0; mf < 6; ++mf) {
        #pragma unroll
        for (int r = 0; r < 4; ++r) {
            const int c = mf * 16 + (lane >> 4) * 4 + r;
            const float bias = pbs[c];
            #pragma unroll
            for (int nf = 0; nf < 4; ++nf) {
                const int q = w * 64 + nf * 16 + lr;
                out[obase + (size_t)c * 65536 + q] = acc[mf][nf][r] + bias;
            }
        }
    }
}

// ---------------- host: Cayley-Dickson table ----------------
static void cd_table(int n, int* S, int* K) {
    if (n == 1) { S[0] = 1; K[0] = 0; return; }
    int m = n / 2;
    int s[64], k[64];
    cd_table(m, s, k);
    for (int i = 0; i < n; ++i) {
        for (int j = 0; j < n; ++j) {
            if (i < m && j < m) { S[i*n+j] = s[i*m+j]; K[i*n+j] = k[i*m+j]; }
            else if (i < m) { int q = j - m; S[i*n+j] = s[q*m+i]; K[i*n+j] = m + k[q*m+i]; }
            else if (j < m) { int p = i - m; int cj = (j == 0) ? 1 : -1;
                              S[i*n+j] = s[p*m+j] * cj; K[i*n+j] = m + k[p*m+j]; }
            else { int p = i - m, q = j - m; int cq = (q == 0) ? 1 : -1;
                   S[i*n+j] = -cq * s[q*m+p]; K[i*n+j] = k[q*m+p]; }
        }
    }
}

extern "C" void kernel_launch(void* const* d_in, const int* in_sizes, int n_in,
                              void* d_out, int out_size, void* d_ws, size_t ws_size,
                              hipStream_t stream) {
    const float* x      = (const float*)d_in[0];
    const float* w_comp = (const float*)d_in[1];
    const float* proj_w = (const float*)d_in[2];
    const float* proj_b = (const float*)d_in[3];
    float* out = (float*)d_out;

    unsigned short* BigT = (unsigned short*)d_ws;
    unsigned short* Yg   = (unsigned short*)((char*)d_ws + 4718592);
    unsigned short* Xw   = (unsigned short*)d_out;   // scratch; overwritten by proj_mfma

    int S16[256], K16[256];
    cd_table(16, S16, K16);
    SedTab tab;
    for (int i = 0; i < 16; ++i)
        for (int j = 0; j < 16; ++j) {
            int k = K16[i * 16 + j];
            tab.idx[j * 16 + k] = (signed char)i;
            tab.sgn[j * 16 + k] = (signed char)S16[i * 16 + j];
        }

    hipLaunchKernelGGL(build_bigT, dim3(9216), dim3(256), 0, stream, w_comp, BigT, tab);
    hipLaunchKernelGGL(window_cast, dim3(2048), dim3(256), 0, stream, x, Xw);
    hipLaunchKernelGGL(gemm_sed8, dim3(1536), dim3(512), 0, stream, Xw, BigT, Yg);
    hipLaunchKernelGGL(proj_mfma, dim3(2048), dim3(256), 0, stream, Yg, proj_w, proj_b, out);
}

// Round 4
// 347.356 us; speedup vs baseline: 1.0494x; 1.0494x over previous
//
#include <hip/hip_runtime.h>
#include <hip/hip_bf16.h>

typedef __attribute__((ext_vector_type(8))) short short8v;
typedef __attribute__((ext_vector_type(4))) float float4v;

struct SedTab { signed char sgn[256]; signed char idx[256]; };

__device__ inline unsigned short f2bf(float f) {
    __hip_bfloat16 h = __float2bfloat16(f);
    return *reinterpret_cast<unsigned short*>(&h);
}
__device__ inline float bf2f(unsigned short u) {
    union { unsigned int i; float f; } x; x.i = ((unsigned)u) << 16; return x.f;
}

#define GLOAD_LDS16(g, l) __builtin_amdgcn_global_load_lds( \
    (const __attribute__((address_space(1))) void*)(g), \
    (__attribute__((address_space(3))) void*)(l), 16, 0, 0)

#define VMCNT(n) asm volatile("s_waitcnt vmcnt(" #n ")" ::: "memory")

// ---------------- Kernel P: build BigT (n-major) bf16 ----------------
__global__ __launch_bounds__(256) void build_bigT(
    const float* __restrict__ w_comp, unsigned short* __restrict__ bigT, SedTab tab)
{
    int e = blockIdx.x * 256 + threadIdx.x;
    if (e >= 1536 * 1536) return;
    int n = e / 1536, k = e - n * 1536;
    int t_out = n / 96, c = n - t_out * 96;
    int t_in = k / 96, m = k - t_in * 96;
    int i = tab.idx[t_in * 16 + t_out];
    float s = (float)tab.sgn[t_in * 16 + t_out];
    float v = s * w_comp[(i * 96 + m) * 96 + c];
    bigT[e] = f2bf(v);
}

// ---------------- Kernel W: window + cast to bf16 ----------------
__global__ __launch_bounds__(256) void window_cast(
    const float* __restrict__ x, unsigned short* __restrict__ xw)
{
    __shared__ unsigned short lds[96][260];
    int blk = blockIdx.x;
    int s1 = blk & 3, hh = (blk >> 2) & 63, b = blk >> 8;
    const float* src = x + (size_t)b * 6291456 + (size_t)(4 * hh + s1) * 256;

    for (int i = threadIdx.x; i < 6144; i += 256) {
        int m = i >> 6;
        int q = (i & 63) << 2;
        float4 v = *(const float4*)(src + (size_t)m * 65536 + q);
        lds[m][q + 0] = f2bf(v.x);
        lds[m][q + 1] = f2bf(v.y);
        lds[m][q + 2] = f2bf(v.z);
        lds[m][q + 3] = f2bf(v.w);
    }
    __syncthreads();
    size_t rowbase = (size_t)((b * 64 + hh) * 64) * 1536 + (size_t)s1 * 384;
    for (int i = threadIdx.x; i < 3072; i += 256) {
        int ww = i / 48, g = i - ww * 48;
        int s2 = g / 12, mg = (g - s2 * 12) * 8;
        int qq = 4 * ww + s2;
        short8v pk;
        #pragma unroll
        for (int j = 0; j < 8; ++j) pk[j] = (short)lds[mg + j][qq];
        *(short8v*)(xw + rowbase + (size_t)ww * 1536 + s2 * 96 + mg) = pk;
    }
}

// ---------------- Kernel G: 256x256 4-phase pipelined bf16 GEMM + GELU ----------------
// M=32768, N=1536, K=1536. BM=BN=256, BK=64, 512 thr, 8 waves (2M x 4N),
// per-wave output 128x64 (acc[8][4]).
// LDS: A 3 slots (staged 2 tiles ahead), B 2 slots (1 ahead) = 160 KiB exact.
// 4 phases per K-tile = (m-half x K-half), 16 MFMA each, setprio-wrapped.
// Stage: ph0/ph1 -> B(kt+1) halves; ph2/ph3 -> A(kt+2) halves (2 loads each).
// Gate once per tile at end: vmcnt(4) = A(kt+1)+B(kt+1) landed, A(kt+2) in
// flight. Never drains to 0 until kt=22 tail.
// XOR involution swizzle (both sides, rule #21): read col chunk
// (ks*4+lg)^(row&7); stage source pre-swizzled kc=((c&7)^(row&7))<<3,
// LDS dest linear (global_load_lds constraint). 0 bank conflicts (R3-verified).
__global__ __launch_bounds__(512, 2) void gemm_sed8(
    const unsigned short* __restrict__ A,
    const unsigned short* __restrict__ Bt,
    unsigned short* __restrict__ Yg)
{
    __shared__ unsigned short As[3][256 * 64];   // 96 KiB
    __shared__ unsigned short Bs[2][256 * 64];   // 64 KiB
    const int t = threadIdx.x;
    const int lane = t & 63, w = t >> 6;
    const int wm = w >> 2, wn = w & 3;           // 2M x 4N
    const int lr = lane & 15, lg = lane >> 4;

    // XCD-aware bijective swizzle: grid 768 = 8 XCD chunks of 96, n-major
    const int bid = blockIdx.x;
    const int wg = (bid & 7) * 96 + (bid >> 3);
    const int nt = wg >> 7, mt = wg & 127;       // 6 nt x 128 mt
    const int m0 = mt * 256, n0 = nt * 256;

    float4v acc[8][4];
    #pragma unroll
    for (int i = 0; i < 8; ++i)
        #pragma unroll
        for (int j = 0; j < 4; ++j) acc[i][j] = (float4v)0.0f;

    auto stageA = [&](int kt, int half, int i) {   // half-tile: 128 rows x 64 k
        const int c = t + i * 512;                 // 0..1023
        const int row = half * 128 + (c >> 3);
        const int kc = ((c & 7) ^ (row & 7)) << 3;
        GLOAD_LDS16(A + (size_t)(m0 + row) * 1536 + kt * 64 + kc,
                    (char*)&As[kt % 3][0] + half * 16384 + c * 16);
    };
    auto stageB = [&](int kt, int half, int i) {
        const int c = t + i * 512;
        const int row = half * 128 + (c >> 3);
        const int kc = ((c & 7) ^ (row & 7)) << 3;
        GLOAD_LDS16(Bt + (size_t)(n0 + row) * 1536 + kt * 64 + kc,
                    (char*)&Bs[kt & 1][0] + half * 16384 + c * 16);
    };

    // prologue: A0 (4), B0 (4), A1 (4) -> vmcnt(4) = A0,B0 landed; A1 in flight
    stageA(0, 0, 0); stageA(0, 0, 1); stageA(0, 1, 0); stageA(0, 1, 1);
    stageB(0, 0, 0); stageB(0, 0, 1); stageB(0, 1, 0); stageB(0, 1, 1);
    stageA(1, 0, 0); stageA(1, 0, 1); stageA(1, 1, 0); stageA(1, 1, 1);
    VMCNT(4);
    __builtin_amdgcn_s_barrier();

    const int c0 = (lg * 8) ^ ((lr & 7) << 3);          // ks=0 col
    const int c1 = (32 + lg * 8) ^ ((lr & 7) << 3);     // ks=1 col

    for (int kt = 0; kt < 24; ++kt) {
        const unsigned short* as = &As[kt % 3][0];
        const unsigned short* bs = &Bs[kt & 1][0];
        const int arow0 = wm * 128 + lr;                 // + mf*16 (+64 for mh1)
        const int brow0 = wn * 64 + lr;

        // ---- ph0: (mh0, ks0) — 8 reads + stage B(kt+1) H0 ----
        short8v a0[4], b0[4];
        #pragma unroll
        for (int mf = 0; mf < 4; ++mf)
            a0[mf] = *(const short8v*)(as + (arow0 + mf * 16) * 64 + c0);
        #pragma unroll
        for (int nf = 0; nf < 4; ++nf)
            b0[nf] = *(const short8v*)(bs + (brow0 + nf * 16) * 64 + c0);
        if (kt < 23) { stageB(kt + 1, 0, 0); stageB(kt + 1, 0, 1); }
        __builtin_amdgcn_s_barrier();
        __builtin_amdgcn_s_setprio(1);
        #pragma unroll
        for (int mf = 0; mf < 4; ++mf)
            #pragma unroll
            for (int nf = 0; nf < 4; ++nf)
                acc[mf][nf] = __builtin_amdgcn_mfma_f32_16x16x32_bf16(
                    a0[mf], b0[nf], acc[mf][nf], 0, 0, 0);
        __builtin_amdgcn_s_setprio(0);
        __builtin_amdgcn_s_barrier();

        // ---- ph1: (mh1, ks0) — 4 reads + stage B(kt+1) H1 ----
        short8v a1[4];
        #pragma unroll
        for (int mf = 0; mf < 4; ++mf)
            a1[mf] = *(const short8v*)(as + (arow0 + 64 + mf * 16) * 64 + c0);
        if (kt < 23) { stageB(kt + 1, 1, 0); stageB(kt + 1, 1, 1); }
        __builtin_amdgcn_s_barrier();
        __builtin_amdgcn_s_setprio(1);
        #pragma unroll
        for (int mf = 0; mf < 4; ++mf)
            #pragma unroll
            for (int nf = 0; nf < 4; ++nf)
                acc[4 + mf][nf] = __builtin_amdgcn_mfma_f32_16x16x32_bf16(
                    a1[mf], b0[nf], acc[4 + mf][nf], 0, 0, 0);
        __builtin_amdgcn_s_setprio(0);
        __builtin_amdgcn_s_barrier();

        // ---- ph2: (mh0, ks1) — 8 reads + stage A(kt+2) H0 ----
        short8v a2[4], b1[4];
        #pragma unroll
        for (int mf = 0; mf < 4; ++mf)
            a2[mf] = *(const short8v*)(as + (arow0 + mf * 16) * 64 + c1);
        #pragma unroll
        for (int nf = 0; nf < 4; ++nf)
            b1[nf] = *(const short8v*)(bs + (brow0 + nf * 16) * 64 + c1);
        if (kt < 22) { stageA(kt + 2, 0, 0); stageA(kt + 2, 0, 1); }
        __builtin_amdgcn_s_barrier();
        __builtin_amdgcn_s_setprio(1);
        #pragma unroll
        for (int mf = 0; mf < 4; ++mf)
            #pragma unroll
            for (int nf = 0; nf < 4; ++nf)
                acc[mf][nf] = __builtin_amdgcn_mfma_f32_16x16x32_bf16(
                    a2[mf], b1[nf], acc[mf][nf], 0, 0, 0);
        __builtin_amdgcn_s_setprio(0);
        __builtin_amdgcn_s_barrier();

        // ---- ph3: (mh1, ks1) — 4 reads + stage A(kt+2) H1 + gate ----
        short8v a3[4];
        #pragma unroll
        for (int mf = 0; mf < 4; ++mf)
            a3[mf] = *(const short8v*)(as + (arow0 + 64 + mf * 16) * 64 + c1);
        if (kt < 22) { stageA(kt + 2, 1, 0); stageA(kt + 2, 1, 1); }
        __builtin_amdgcn_s_barrier();
        __builtin_amdgcn_s_setprio(1);
        #pragma unroll
        for (int mf = 0; mf < 4; ++mf)
            #pragma unroll
            for (int nf = 0; nf < 4; ++nf)
                acc[4 + mf][nf] = __builtin_amdgcn_mfma_f32_16x16x32_bf16(
                    a3[mf], b1[nf], acc[4 + mf][nf], 0, 0, 0);
        __builtin_amdgcn_s_setprio(0);
        // gate: next tile's A+B landed; A(kt+2)'s 4 loads stay in flight
        if (kt < 22)       { VMCNT(4); }
        else if (kt == 22) { VMCNT(0); }
        __builtin_amdgcn_s_barrier();
    }

    // epilogue: exact GELU, cast bf16, store
    #pragma unroll
    for (int mf = 0; mf < 8; ++mf) {
        #pragma unroll
        for (int r = 0; r < 4; ++r) {
            const int gm = m0 + wm * 128 + mf * 16 + lg * 4 + r;
            #pragma unroll
            for (int nf = 0; nf < 4; ++nf) {
                const int gn = n0 + wn * 64 + nf * 16 + lr;
                float v = acc[mf][nf][r];
                float g = 0.5f * v * (1.0f + erff(v * 0.70710678118654752f));
                Yg[(size_t)gm * 1536 + gn] = f2bf(g);
            }
        }
    }
}

// ---------------- Kernel R: MFMA projection + bias + NCHW store ----------------
__global__ __launch_bounds__(256, 2) void proj_mfma(
    const unsigned short* __restrict__ Yg,
    const float* __restrict__ pw, const float* __restrict__ pb,
    float* __restrict__ out)
{
    __shared__ unsigned short gys[256 * 104];
    __shared__ unsigned short pws[96 * 104];
    __shared__ float pbs[96];

    const int blk = blockIdx.x;
    const int s1 = blk & 3, hh = (blk >> 2) & 63, b = blk >> 8;
    const int t = threadIdx.x;
    const int lane = t & 63, w = t >> 6;
    const int lr = lane & 15;

    for (int i = t; i < 9216; i += 256) {
        int r = i / 96, c = i - r * 96;
        pws[r * 104 + c] = f2bf(pw[i]);
    }
    if (t < 96) pbs[t] = pb[t];

    size_t rowbase = (size_t)((b * 64 + hh) * 64) * 1536 + (size_t)s1 * 384;
    for (int i = t; i < 3072; i += 256) {
        int ww = i / 48, v = i - ww * 48;
        short8v pk = *(const short8v*)(Yg + rowbase + (size_t)ww * 1536 + v * 8);
        int s2 = v / 12;
        int c = (v - s2 * 12) * 8;
        int q = 4 * ww + s2;
        *(short8v*)(&gys[q * 104 + c]) = pk;
    }
    __syncthreads();

    float4v acc[6][4];
    #pragma unroll
    for (int i = 0; i < 6; ++i)
        #pragma unroll
        for (int j = 0; j < 4; ++j) acc[i][j] = (float4v)0.0f;

    #pragma unroll
    for (int ks = 0; ks < 3; ++ks) {
        const int lk = ks * 32 + ((lane >> 4) << 3);
        short8v af[6], bf[4];
        #pragma unroll
        for (int mf = 0; mf < 6; ++mf)
            af[mf] = *(const short8v*)(&pws[(mf * 16 + lr) * 104 + lk]);
        #pragma unroll
        for (int nf = 0; nf < 4; ++nf)
            bf[nf] = *(const short8v*)(&gys[(w * 64 + nf * 16 + lr) * 104 + lk]);
        #pragma unroll
        for (int mf = 0; mf < 6; ++mf)
            #pragma unroll
            for (int nf = 0; nf < 4; ++nf)
                acc[mf][nf] = __builtin_amdgcn_mfma_f32_16x16x32_bf16(
                    af[mf], bf[nf], acc[mf][nf], 0, 0, 0);
    }

    const int p = 4 * hh + s1;
    const size_t obase = (size_t)b * 6291456 + (size_t)p * 256;
    #pragma unroll
    for (int mf = 0; mf < 6; ++mf) {
        #pragma unroll
        for (int r = 0; r < 4; ++r) {
            const int c = mf * 16 + (lane >> 4) * 4 + r;
            const float bias = pbs[c];
            #pragma unroll
            for (int nf = 0; nf < 4; ++nf) {
                const int q = w * 64 + nf * 16 + lr;
                out[obase + (size_t)c * 65536 + q] = acc[mf][nf][r] + bias;
            }
        }
    }
}

// ---------------- host: Cayley-Dickson table ----------------
static void cd_table(int n, int* S, int* K) {
    if (n == 1) { S[0] = 1; K[0] = 0; return; }
    int m = n / 2;
    int s[64], k[64];
    cd_table(m, s, k);
    for (int i = 0; i < n; ++i) {
        for (int j = 0; j < n; ++j) {
            if (i < m && j < m) { S[i*n+j] = s[i*m+j]; K[i*n+j] = k[i*m+j]; }
            else if (i < m) { int q = j - m; S[i*n+j] = s[q*m+i]; K[i*n+j] = m + k[q*m+i]; }
            else if (j < m) { int p = i - m; int cj = (j == 0) ? 1 : -1;
                              S[i*n+j] = s[p*m+j] * cj; K[i*n+j] = m + k[p*m+j]; }
            else { int p = i - m, q = j - m; int cq = (q == 0) ? 1 : -1;
                   S[i*n+j] = -cq * s[q*m+p]; K[i*n+j] = k[q*m+p]; }
        }
    }
}

extern "C" void kernel_launch(void* const* d_in, const int* in_sizes, int n_in,
                              void* d_out, int out_size, void* d_ws, size_t ws_size,
                              hipStream_t stream) {
    const float* x      = (const float*)d_in[0];
    const float* w_comp = (const float*)d_in[1];
    const float* proj_w = (const float*)d_in[2];
    const float* proj_b = (const float*)d_in[3];
    float* out = (float*)d_out;

    unsigned short* BigT = (unsigned short*)d_ws;
    unsigned short* Yg   = (unsigned short*)((char*)d_ws + 4718592);
    unsigned short* Xw   = (unsigned short*)d_out;   // scratch; overwritten by proj_mfma

    int S16[256], K16[256];
    cd_table(16, S16, K16);
    SedTab tab;
    for (int i = 0; i < 16; ++i)
        for (int j = 0; j < 16; ++j) {
            int k = K16[i * 16 + j];
            tab.idx[j * 16 + k] = (signed char)i;
            tab.sgn[j * 16 + k] = (signed char)S16[i * 16 + j];
        }

    hipLaunchKernelGGL(build_bigT, dim3(9216), dim3(256), 0, stream, w_comp, BigT, tab);
    hipLaunchKernelGGL(window_cast, dim3(2048), dim3(256), 0, stream, x, Xw);
    hipLaunchKernelGGL(gemm_sed8, dim3(768), dim3(512), 0, stream, Xw, BigT, Yg);
    hipLaunchKernelGGL(proj_mfma, dim3(2048), dim3(256), 0, stream, Yg, proj_w, proj_b, out);
}

// Round 5
// 327.645 us; speedup vs baseline: 1.1125x; 1.0602x over previous
//
#include <hip/hip_runtime.h>
#include <hip/hip_bf16.h>

typedef __attribute__((ext_vector_type(8))) short short8v;
typedef __attribute__((ext_vector_type(4))) float float4v;

struct SedTab { signed char sgn[256]; signed char idx[256]; };

__device__ inline unsigned short f2bf(float f) {
    __hip_bfloat16 h = __float2bfloat16(f);
    return *reinterpret_cast<unsigned short*>(&h);
}
__device__ inline float bf2f(unsigned short u) {
    union { unsigned int i; float f; } x; x.i = ((unsigned)u) << 16; return x.f;
}

#define GLOAD_LDS16(g, l) __builtin_amdgcn_global_load_lds( \
    (const __attribute__((address_space(1))) void*)(g), \
    (__attribute__((address_space(3))) void*)(l), 16, 0, 0)

#define VMCNT(n) asm volatile("s_waitcnt vmcnt(" #n ")" ::: "memory")

// ---------------- Kernel P: build BigT (n-major) bf16 ----------------
__global__ __launch_bounds__(256) void build_bigT(
    const float* __restrict__ w_comp, unsigned short* __restrict__ bigT, SedTab tab)
{
    int e = blockIdx.x * 256 + threadIdx.x;
    if (e >= 1536 * 1536) return;
    int n = e / 1536, k = e - n * 1536;
    int t_out = n / 96, c = n - t_out * 96;
    int t_in = k / 96, m = k - t_in * 96;
    int i = tab.idx[t_in * 16 + t_out];
    float s = (float)tab.sgn[t_in * 16 + t_out];
    float v = s * w_comp[(i * 96 + m) * 96 + c];
    bigT[e] = f2bf(v);
}

// ---------------- Kernel W: window + cast to bf16 ----------------
__global__ __launch_bounds__(256) void window_cast(
    const float* __restrict__ x, unsigned short* __restrict__ xw)
{
    __shared__ unsigned short lds[96][260];
    int blk = blockIdx.x;
    int s1 = blk & 3, hh = (blk >> 2) & 63, b = blk >> 8;
    const float* src = x + (size_t)b * 6291456 + (size_t)(4 * hh + s1) * 256;

    for (int i = threadIdx.x; i < 6144; i += 256) {
        int m = i >> 6;
        int q = (i & 63) << 2;
        float4 v = *(const float4*)(src + (size_t)m * 65536 + q);
        lds[m][q + 0] = f2bf(v.x);
        lds[m][q + 1] = f2bf(v.y);
        lds[m][q + 2] = f2bf(v.z);
        lds[m][q + 3] = f2bf(v.w);
    }
    __syncthreads();
    size_t rowbase = (size_t)((b * 64 + hh) * 64) * 1536 + (size_t)s1 * 384;
    for (int i = threadIdx.x; i < 3072; i += 256) {
        int ww = i / 48, g = i - ww * 48;
        int s2 = g / 12, mg = (g - s2 * 12) * 8;
        int qq = 4 * ww + s2;
        short8v pk;
        #pragma unroll
        for (int j = 0; j < 8; ++j) pk[j] = (short)lds[mg + j][qq];
        *(short8v*)(xw + rowbase + (size_t)ww * 1536 + s2 * 96 + mg) = pk;
    }
}

// ---------------- Kernel G: 256x256 4-phase pipelined bf16 GEMM + GELU ----------------
// M=32768, N=1536, K=1536. BM=BN=256, BK=64, 512 thr, 8 waves (2M x 4N),
// per-wave output 128x64 (acc[8][4]).
// ONE barrier per phase: {ds_read issue | stage issue -> s_barrier -> MFMA}.
// After its MFMA cluster a wave immediately issues next-phase ds_reads while
// sibling waves still MFMA (setprio arbitrates) -> LDS pipe and MFMA pipe
// overlap across the 2 waves/SIMD. Slot-WAR safety: stage into slot s (kt.ph2)
// is >=3 barriers after slot-s readers' reads completed (their ph3 lgkm wait).
// LDS: A 3 slots (2 tiles ahead), B 2 slots (1 ahead) = 160 KiB exact.
// Gate once per tile: vmcnt(4) (A(kt+2) stays in flight); never 0 till kt=22.
// XOR involution swizzle both sides (rule #21), R3/R4-verified 0 conflicts.
__global__ __launch_bounds__(512, 2) void gemm_sed8(
    const unsigned short* __restrict__ A,
    const unsigned short* __restrict__ Bt,
    unsigned short* __restrict__ Yg)
{
    __shared__ unsigned short As[3][256 * 64];   // 96 KiB (32768 B per slot)
    __shared__ unsigned short Bs[2][256 * 64];   // 64 KiB
    const int t = threadIdx.x;
    const int lane = t & 63, w = t >> 6;
    const int wm = w >> 2, wn = w & 3;           // 2M x 4N
    const int lr = lane & 15, lg = lane >> 4;

    // XCD-aware bijective swizzle: grid 768 = 8 XCD chunks of 96, n-major
    const int bid = blockIdx.x;
    const int wg = (bid & 7) * 96 + (bid >> 3);
    const int nt = wg >> 7, mt = wg & 127;       // 6 nt x 128 mt
    const int m0 = mt * 256, n0 = nt * 256;

    float4v acc[8][4];
    #pragma unroll
    for (int i = 0; i < 8; ++i)
        #pragma unroll
        for (int j = 0; j < 4; ++j) acc[i][j] = (float4v)0.0f;

    // per-thread staging constants (hoisted): chunk ids t and t+512
    const int r0c = t >> 3,          r1c = (t + 512) >> 3;
    const int kc0 = ((t & 7) ^ (r0c & 7)) << 3;
    const int kc1 = (((t + 512) & 7) ^ (r1c & 7)) << 3;
    const unsigned short* gA0 = A  + (size_t)(m0 + r0c) * 1536 + kc0;
    const unsigned short* gA1 = A  + (size_t)(m0 + r1c) * 1536 + kc1;
    const unsigned short* gB0 = Bt + (size_t)(n0 + r0c) * 1536 + kc0;
    const unsigned short* gB1 = Bt + (size_t)(n0 + r1c) * 1536 + kc1;
    const int d0 = t * 16, d1 = (t + 512) * 16;  // LDS dest byte offsets

    auto stage2 = [&](const unsigned short* g0, const unsigned short* g1,
                      char* ldst, int ko, int half) {
        GLOAD_LDS16(g0 + ko + half * 196608, ldst + half * 16384 + d0);
        GLOAD_LDS16(g1 + ko + half * 196608, ldst + half * 16384 + d1);
    };

    char* a_rd = (char*)&As[0][0];
    char* a_md = (char*)&As[0][0] + 32768;
    char* a_wr = (char*)&As[0][0] + 65536;
    char* b_rd = (char*)&Bs[0][0];
    char* b_wr = (char*)&Bs[0][0] + 32768;

    // prologue: A0 (4 loads), B0 (4), A1 (4) -> vmcnt(4): A0,B0 landed, A1 in flight
    stage2(gA0, gA1, a_rd, 0, 0);  stage2(gA0, gA1, a_rd, 0, 1);
    stage2(gB0, gB1, b_rd, 0, 0);  stage2(gB0, gB1, b_rd, 0, 1);
    stage2(gA0, gA1, a_md, 64, 0); stage2(gA0, gA1, a_md, 64, 1);
    VMCNT(4);
    __builtin_amdgcn_s_barrier();

    const int c0 = (lg * 8) ^ ((lr & 7) << 3);          // ks=0 col
    const int c1 = (32 + lg * 8) ^ ((lr & 7) << 3);     // ks=1 col
    const int arow0 = wm * 128 + lr;
    const int brow0 = wn * 64 + lr;

    int koB = 64, koA = 128;                            // (kt+1)*64, (kt+2)*64

    for (int kt = 0; kt < 24; ++kt) {
        const unsigned short* as = (const unsigned short*)a_rd;
        const unsigned short* bs = (const unsigned short*)b_rd;

        // ---- ph0: (mh0, ks0) — 8 reads + stage B(kt+1) H0 ----
        short8v a0[4], b0[4];
        #pragma unroll
        for (int mf = 0; mf < 4; ++mf)
            a0[mf] = *(const short8v*)(as + (arow0 + mf * 16) * 64 + c0);
        #pragma unroll
        for (int nf = 0; nf < 4; ++nf)
            b0[nf] = *(const short8v*)(bs + (brow0 + nf * 16) * 64 + c0);
        if (kt < 23) stage2(gB0, gB1, b_wr, koB, 0);
        __builtin_amdgcn_s_barrier();
        __builtin_amdgcn_s_setprio(1);
        #pragma unroll
        for (int mf = 0; mf < 4; ++mf)
            #pragma unroll
            for (int nf = 0; nf < 4; ++nf)
                acc[mf][nf] = __builtin_amdgcn_mfma_f32_16x16x32_bf16(
                    a0[mf], b0[nf], acc[mf][nf], 0, 0, 0);
        __builtin_amdgcn_s_setprio(0);

        // ---- ph1: (mh1, ks0) — 4 reads + stage B(kt+1) H1 ----
        short8v a1[4];
        #pragma unroll
        for (int mf = 0; mf < 4; ++mf)
            a1[mf] = *(const short8v*)(as + (arow0 + 64 + mf * 16) * 64 + c0);
        if (kt < 23) stage2(gB0, gB1, b_wr, koB, 1);
        __builtin_amdgcn_s_barrier();
        __builtin_amdgcn_s_setprio(1);
        #pragma unroll
        for (int mf = 0; mf < 4; ++mf)
            #pragma unroll
            for (int nf = 0; nf < 4; ++nf)
                acc[4 + mf][nf] = __builtin_amdgcn_mfma_f32_16x16x32_bf16(
                    a1[mf], b0[nf], acc[4 + mf][nf], 0, 0, 0);
        __builtin_amdgcn_s_setprio(0);

        // ---- ph2: (mh0, ks1) — 8 reads + stage A(kt+2) H0 ----
        short8v a2[4], b1[4];
        #pragma unroll
        for (int mf = 0; mf < 4; ++mf)
            a2[mf] = *(const short8v*)(as + (arow0 + mf * 16) * 64 + c1);
        #pragma unroll
        for (int nf = 0; nf < 4; ++nf)
            b1[nf] = *(const short8v*)(bs + (brow0 + nf * 16) * 64 + c1);
        if (kt < 22) stage2(gA0, gA1, a_wr, koA, 0);
        __builtin_amdgcn_s_barrier();
        __builtin_amdgcn_s_setprio(1);
        #pragma unroll
        for (int mf = 0; mf < 4; ++mf)
            #pragma unroll
            for (int nf = 0; nf < 4; ++nf)
                acc[mf][nf] = __builtin_amdgcn_mfma_f32_16x16x32_bf16(
                    a2[mf], b1[nf], acc[mf][nf], 0, 0, 0);
        __builtin_amdgcn_s_setprio(0);

        // ---- ph3: (mh1, ks1) — 4 reads + stage A(kt+2) H1 + gate ----
        short8v a3[4];
        #pragma unroll
        for (int mf = 0; mf < 4; ++mf)
            a3[mf] = *(const short8v*)(as + (arow0 + 64 + mf * 16) * 64 + c1);
        if (kt < 22) stage2(gA0, gA1, a_wr, koA, 1);
        if (kt < 22)       { VMCNT(4); }
        else if (kt == 22) { VMCNT(0); }
        __builtin_amdgcn_s_barrier();
        __builtin_amdgcn_s_setprio(1);
        #pragma unroll
        for (int mf = 0; mf < 4; ++mf)
            #pragma unroll
            for (int nf = 0; nf < 4; ++nf)
                acc[4 + mf][nf] = __builtin_amdgcn_mfma_f32_16x16x32_bf16(
                    a3[mf], b1[nf], acc[4 + mf][nf], 0, 0, 0);
        __builtin_amdgcn_s_setprio(0);

        // rotate slots
        char* tmp = a_rd; a_rd = a_md; a_md = a_wr; a_wr = tmp;
        tmp = b_rd; b_rd = b_wr; b_wr = tmp;
        koB += 64; koA += 64;
    }

    // epilogue: exact GELU, cast bf16, store
    #pragma unroll
    for (int mf = 0; mf < 8; ++mf) {
        #pragma unroll
        for (int r = 0; r < 4; ++r) {
            const int gm = m0 + wm * 128 + mf * 16 + lg * 4 + r;
            #pragma unroll
            for (int nf = 0; nf < 4; ++nf) {
                const int gn = n0 + wn * 64 + nf * 16 + lr;
                float v = acc[mf][nf][r];
                float g = 0.5f * v * (1.0f + erff(v * 0.70710678118654752f));
                Yg[(size_t)gm * 1536 + gn] = f2bf(g);
            }
        }
    }
}

// ---------------- Kernel R: MFMA projection + bias + NCHW store ----------------
__global__ __launch_bounds__(256, 2) void proj_mfma(
    const unsigned short* __restrict__ Yg,
    const float* __restrict__ pw, const float* __restrict__ pb,
    float* __restrict__ out)
{
    __shared__ unsigned short gys[256 * 104];
    __shared__ unsigned short pws[96 * 104];
    __shared__ float pbs[96];

    const int blk = blockIdx.x;
    const int s1 = blk & 3, hh = (blk >> 2) & 63, b = blk >> 8;
    const int t = threadIdx.x;
    const int lane = t & 63, w = t >> 6;
    const int lr = lane & 15;

    for (int i = t; i < 9216; i += 256) {
        int r = i / 96, c = i - r * 96;
        pws[r * 104 + c] = f2bf(pw[i]);
    }
    if (t < 96) pbs[t] = pb[t];

    size_t rowbase = (size_t)((b * 64 + hh) * 64) * 1536 + (size_t)s1 * 384;
    for (int i = t; i < 3072; i += 256) {
        int ww = i / 48, v = i - ww * 48;
        short8v pk = *(const short8v*)(Yg + rowbase + (size_t)ww * 1536 + v * 8);
        int s2 = v / 12;
        int c = (v - s2 * 12) * 8;
        int q = 4 * ww + s2;
        *(short8v*)(&gys[q * 104 + c]) = pk;
    }
    __syncthreads();

    float4v acc[6][4];
    #pragma unroll
    for (int i = 0; i < 6; ++i)
        #pragma unroll
        for (int j = 0; j < 4; ++j) acc[i][j] = (float4v)0.0f;

    #pragma unroll
    for (int ks = 0; ks < 3; ++ks) {
        const int lk = ks * 32 + ((lane >> 4) << 3);
        short8v af[6], bf[4];
        #pragma unroll
        for (int mf = 0; mf < 6; ++mf)
            af[mf] = *(const short8v*)(&pws[(mf * 16 + lr) * 104 + lk]);
        #pragma unroll
        for (int nf = 0; nf < 4; ++nf)
            bf[nf] = *(const short8v*)(&gys[(w * 64 + nf * 16 + lr) * 104 + lk]);
        #pragma unroll
        for (int mf = 0; mf < 6; ++mf)
            #pragma unroll
            for (int nf = 0; nf < 4; ++nf)
                acc[mf][nf] = __builtin_amdgcn_mfma_f32_16x16x32_bf16(
                    af[mf], bf[nf], acc[mf][nf], 0, 0, 0);
    }

    const int p = 4 * hh + s1;
    const size_t obase = (size_t)b * 6291456 + (size_t)p * 256;
    #pragma unroll
    for (int mf = 0; mf < 6; ++mf) {
        #pragma unroll
        for (int r = 0; r < 4; ++r) {
            const int c = mf * 16 + (lane >> 4) * 4 + r;
            const float bias = pbs[c];
            #pragma unroll
            for (int nf = 0; nf < 4; ++nf) {
                const int q = w * 64 + nf * 16 + lr;
                out[obase + (size_t)c * 65536 + q] = acc[mf][nf][r] + bias;
            }
        }
    }
}

// ---------------- host: Cayley-Dickson table ----------------
static void cd_table(int n, int* S, int* K) {
    if (n == 1) { S[0] = 1; K[0] = 0; return; }
    int m = n / 2;
    int s[64], k[64];
    cd_table(m, s, k);
    for (int i = 0; i < n; ++i) {
        for (int j = 0; j < n; ++j) {
            if (i < m && j < m) { S[i*n+j] = s[i*m+j]; K[i*n+j] = k[i*m+j]; }
            else if (i < m) { int q = j - m; S[i*n+j] = s[q*m+i]; K[i*n+j] = m + k[q*m+i]; }
            else if (j < m) { int p = i - m; int cj = (j == 0) ? 1 : -1;
                              S[i*n+j] = s[p*m+j] * cj; K[i*n+j] = m + k[p*m+j]; }
            else { int p = i - m, q = j - m; int cq = (q == 0) ? 1 : -1;
                   S[i*n+j] = -cq * s[q*m+p]; K[i*n+j] = k[q*m+p]; }
        }
    }
}

extern "C" void kernel_launch(void* const* d_in, const int* in_sizes, int n_in,
                              void* d_out, int out_size, void* d_ws, size_t ws_size,
                              hipStream_t stream) {
    const float* x      = (const float*)d_in[0];
    const float* w_comp = (const float*)d_in[1];
    const float* proj_w = (const float*)d_in[2];
    const float* proj_b = (const float*)d_in[3];
    float* out = (float*)d_out;

    unsigned short* BigT = (unsigned short*)d_ws;
    unsigned short* Yg   = (unsigned short*)((char*)d_ws + 4718592);
    unsigned short* Xw   = (unsigned short*)d_out;   // scratch; overwritten by proj_mfma

    int S16[256], K16[256];
    cd_table(16, S16, K16);
    SedTab tab;
    for (int i = 0; i < 16; ++i)
        for (int j = 0; j < 16; ++j) {
            int k = K16[i * 16 + j];
            tab.idx[j * 16 + k] = (signed char)i;
            tab.sgn[j * 16 + k] = (signed char)S16[i * 16 + j];
        }

    hipLaunchKernelGGL(build_bigT, dim3(9216), dim3(256), 0, stream, w_comp, BigT, tab);
    hipLaunchKernelGGL(window_cast, dim3(2048), dim3(256), 0, stream, x, Xw);
    hipLaunchKernelGGL(gemm_sed8, dim3(768), dim3(512), 0, stream, Xw, BigT, Yg);
    hipLaunchKernelGGL(proj_mfma, dim3(2048), dim3(256), 0, stream, Yg, proj_w, proj_b, out);
}